// Round 3
// baseline (1499.492 us; speedup 1.0000x reference)
//
#include <hip/hip_runtime.h>

#define NN 200000
#define NE 5000000
#define DIN 128
#define HID 16
#define DOUT 2
#define NB 782   // ceil(NN/256) buckets of 256 consecutive dst nodes
#define PB 512   // partition grid blocks
#define PT 256   // partition block threads

static_assert((NN + 255) / 256 == NB, "bucket count");

// ---------------- edge partition (counting sort by dst>>8, no global atomics) ----------------

// Pass A: per-block LDS histogram of dst buckets. blockHist layout: [k * PB + b].
__global__ __launch_bounds__(PT) void hist_pass(const int* __restrict__ dst,
                                                int* __restrict__ blockHist) {
    __shared__ int h[NB];
    for (int k = threadIdx.x; k < NB; k += PT) h[k] = 0;
    __syncthreads();
    for (int i = blockIdx.x * PT + threadIdx.x; i < NE; i += PB * PT)
        atomicAdd(&h[dst[i] >> 8], 1);
    __syncthreads();
    for (int k = threadIdx.x; k < NB; k += PT) blockHist[k * PB + blockIdx.x] = h[k];
}

// Scan: per-bucket totals -> bucket bases -> per-(bucket,block) start offsets (in place).
__global__ __launch_bounds__(1024) void scan_pass(int* __restrict__ blockHist,
                                                  int* __restrict__ bucketStart) {
    __shared__ int tot[NB];
    for (int k = threadIdx.x; k < NB; k += 1024) {
        const int4* p = reinterpret_cast<const int4*>(blockHist + k * PB);
        int s = 0;
#pragma unroll 8
        for (int b = 0; b < PB / 4; ++b) { int4 v = p[b]; s += v.x + v.y + v.z + v.w; }
        tot[k] = s;
    }
    __syncthreads();
    if (threadIdx.x == 0) {  // serial exclusive scan over 782 bucket totals
        int car = 0;
        for (int k = 0; k < NB; ++k) { int t = tot[k]; tot[k] = car; car += t; }
    }
    __syncthreads();
    for (int k = threadIdx.x; k < NB; k += 1024) {
        int run = tot[k];
        bucketStart[k] = run;
        int4* p = reinterpret_cast<int4*>(blockHist + k * PB);
#pragma unroll 4
        for (int b = 0; b < PB / 4; ++b) {
            int4 v = p[b];
            int4 o;
            o.x = run; run += v.x;
            o.y = run; run += v.y;
            o.z = run; run += v.z;
            o.w = run; run += v.w;
            p[b] = o;
        }
    }
    if (threadIdx.x == 0) bucketStart[NB] = NE;
}

// Pass B: scatter edges to bucket-sorted order. pedge = (src << 8) | (dst & 255).
__global__ __launch_bounds__(PT) void scatter_pass(const int* __restrict__ src,
                                                   const int* __restrict__ dst,
                                                   const int* __restrict__ blockHist,
                                                   unsigned* __restrict__ pedge) {
    __shared__ int cur[NB];
    for (int k = threadIdx.x; k < NB; k += PT) cur[k] = blockHist[k * PB + blockIdx.x];
    __syncthreads();
    for (int i = blockIdx.x * PT + threadIdx.x; i < NE; i += PB * PT) {
        int d = dst[i];
        int pos = atomicAdd(&cur[d >> 8], 1);  // LDS atomic only
        pedge[pos] = ((unsigned)src[i] << 8) | (unsigned)(d & 255);
    }
}

// Per-node degree (in-degree + self loop) -> dis = rsqrt(deg), from partitioned edges.
__global__ __launch_bounds__(256) void deg_dis(const unsigned* __restrict__ pedge,
                                               const int* __restrict__ bucketStart,
                                               float* __restrict__ dis) {
    __shared__ int cnt[256];
    int t = threadIdx.x;
    cnt[t] = 1;  // self loop
    __syncthreads();
    int e0 = bucketStart[blockIdx.x], e1 = bucketStart[blockIdx.x + 1];
    for (int e = e0 + t; e < e1; e += 256) atomicAdd(&cnt[pedge[e] & 255u], 1);
    __syncthreads();
    int node = (blockIdx.x << 8) + t;
    if (node < NN) dis[node] = rsqrtf((float)cnt[t]);
}

// ---------------- dense GEMMs, epilogue-scaled by dis[row] ----------------

__global__ __launch_bounds__(256) void gemm_x_w1(const float* __restrict__ x,
                                                 const float* __restrict__ W,
                                                 const float* __restrict__ dis,
                                                 float* __restrict__ out) {
    __shared__ float w[DIN * HID];
    for (int t = threadIdx.x; t < DIN * HID; t += 256) w[t] = W[t];
    __syncthreads();
    int row = blockIdx.x * 16 + (threadIdx.x >> 4);
    int c = threadIdx.x & 15;
    if (row >= NN) return;
    const float4* xr = reinterpret_cast<const float4*>(x + (size_t)row * DIN);
    float acc = 0.f;
#pragma unroll
    for (int k4 = 0; k4 < DIN / 4; ++k4) {
        float4 v = xr[k4];
        acc += v.x * w[(4 * k4 + 0) * HID + c] + v.y * w[(4 * k4 + 1) * HID + c]
             + v.z * w[(4 * k4 + 2) * HID + c] + v.w * w[(4 * k4 + 3) * HID + c];
    }
    out[row * HID + c] = acc * dis[row];
}

__global__ __launch_bounds__(256) void gemm_h_w16(const float* __restrict__ h,
                                                  const float* __restrict__ W,
                                                  const float* __restrict__ dis,
                                                  float* __restrict__ out) {
    __shared__ float w[HID * HID];
    if (threadIdx.x < HID * HID) w[threadIdx.x] = W[threadIdx.x];
    __syncthreads();
    int row = blockIdx.x * 16 + (threadIdx.x >> 4);
    int c = threadIdx.x & 15;
    if (row >= NN) return;
    const float4* hr = reinterpret_cast<const float4*>(h + (size_t)row * HID);
    float acc = 0.f;
#pragma unroll
    for (int k4 = 0; k4 < HID / 4; ++k4) {
        float4 v = hr[k4];
        acc += v.x * w[(4 * k4 + 0) * HID + c] + v.y * w[(4 * k4 + 1) * HID + c]
             + v.z * w[(4 * k4 + 2) * HID + c] + v.w * w[(4 * k4 + 3) * HID + c];
    }
    out[row * HID + c] = acc * dis[row];
}

__global__ __launch_bounds__(256) void gemm_h_w2(const float* __restrict__ h,
                                                 const float* __restrict__ W,
                                                 const float* __restrict__ dis,
                                                 float* __restrict__ out) {
    int t = blockIdx.x * 256 + threadIdx.x;
    int row = t >> 1;
    int c = t & 1;
    if (row >= NN) return;
    const float* hr = h + (size_t)row * HID;
    float acc = 0.f;
#pragma unroll
    for (int k = 0; k < HID; ++k) acc += hr[k] * W[k * DOUT + c];
    out[row * DOUT + c] = acc * dis[row];
}

// ---------------- bucket-local aggregation (LDS atomics only) ----------------

// One block per bucket of 256 dst nodes. xs rows are pre-scaled by dis[src];
// message = xs[src] * dis[dst]; self-loop = xs[node] * dis[node]. Fused +bias, relu.
__global__ __launch_bounds__(256) void agg16(const unsigned* __restrict__ pedge,
                                             const int* __restrict__ bucketStart,
                                             const float* __restrict__ dis,
                                             const float* __restrict__ xs,
                                             const float* __restrict__ bias, int relu,
                                             float* __restrict__ out) {
    __shared__ float acc[256 * HID];  // 16 KB
    __shared__ float dl[256];
    int t = threadIdx.x;
    int base = blockIdx.x << 8;
    int node = base + t;
    dl[t] = (node < NN) ? dis[node] : 0.f;
    __syncthreads();
    for (int i = t; i < 256 * HID; i += 256) {  // self-loop init: xs[node]*dis[node]
        int gi = (base << 4) + i;
        acc[i] = (gi < NN * HID) ? xs[gi] * dl[i >> 4] : 0.f;
    }
    __syncthreads();
    int e0 = bucketStart[blockIdx.x], e1 = bucketStart[blockIdx.x + 1];
    int c = t & 15;
    for (int e = e0 + (t >> 4); e < e1; e += 16) {
        unsigned p = pedge[e];
        int s = p >> 8;
        int d = p & 255u;
        atomicAdd(&acc[(d << 4) + c], xs[(s << 4) + c] * dl[d]);
    }
    __syncthreads();
    for (int i = t; i < 256 * HID; i += 256) {
        int gi = (base << 4) + i;
        if (gi < NN * HID) {
            float v = acc[i] + bias[i & 15];
            out[gi] = relu ? fmaxf(v, 0.f) : v;
        }
    }
}

// conv2 aggregation + bias + 2-class log_softmax, coalesced store to d_out.
__global__ __launch_bounds__(256) void agg2_lsm(const unsigned* __restrict__ pedge,
                                                const int* __restrict__ bucketStart,
                                                const float* __restrict__ dis,
                                                const float* __restrict__ xs,
                                                const float* __restrict__ bias,
                                                float* __restrict__ out) {
    __shared__ float acc[256 * DOUT];
    __shared__ float dl[256];
    int t = threadIdx.x;
    int base = blockIdx.x << 8;
    int node = base + t;
    float d0 = (node < NN) ? dis[node] : 0.f;
    dl[t] = d0;
    if (node < NN) {
        float2 v = reinterpret_cast<const float2*>(xs)[node];
        acc[t * 2 + 0] = v.x * d0;
        acc[t * 2 + 1] = v.y * d0;
    } else {
        acc[t * 2 + 0] = 0.f;
        acc[t * 2 + 1] = 0.f;
    }
    __syncthreads();
    int e0 = bucketStart[blockIdx.x], e1 = bucketStart[blockIdx.x + 1];
    int c = t & 1;
    for (int e = e0 + (t >> 1); e < e1; e += 128) {
        unsigned p = pedge[e];
        int s = p >> 8;
        int d = p & 255u;
        atomicAdd(&acc[d * 2 + c], xs[s * 2 + c] * dl[d]);
    }
    __syncthreads();
    if (node < NN) {
        float v0 = acc[t * 2 + 0] + bias[0];
        float v1 = acc[t * 2 + 1] + bias[1];
        float m = fmaxf(v0, v1);
        float lse = m + logf(__expf(v0 - m) + __expf(v1 - m));
        reinterpret_cast<float2*>(out)[node] = make_float2(v0 - lse, v1 - lse);
    }
}

// ---------------- launch ----------------

extern "C" void kernel_launch(void* const* d_in, const int* in_sizes, int n_in,
                              void* d_out, int out_size, void* d_ws, size_t ws_size,
                              hipStream_t stream) {
    const float* x = (const float*)d_in[0];
    const int* ei = (const int*)d_in[1];
    const float* W1 = (const float*)d_in[2];
    const float* b1 = (const float*)d_in[3];
    const float* W3 = (const float*)d_in[4];
    const float* b3 = (const float*)d_in[5];
    const float* W2 = (const float*)d_in[6];
    const float* b2 = (const float*)d_in[7];
    float* out = (float*)d_out;

    const int* src = ei;       // edge_index[0]
    const int* dst = ei + NE;  // edge_index[1]

    // workspace layout
    char* ws = (char*)d_ws;
    unsigned* pedge = (unsigned*)ws;                    // NE
    int* blockHist = (int*)(ws + sizeof(unsigned) * NE);  // NB*PB
    int* bucketStart = blockHist + NB * PB;             // NB+1
    float* dis = (float*)(bucketStart + NB + 1);        // NN
    float* bufA = dis + NN;                             // NN*HID
    float* bufB = bufA + NN * HID;                      // NN*HID

    const int B = 256;
    auto cdiv = [](long long a, long long b) { return (int)((a + b - 1) / b); };

    // partition + normalization
    hist_pass<<<PB, PT, 0, stream>>>(dst, blockHist);
    scan_pass<<<1, 1024, 0, stream>>>(blockHist, bucketStart);
    scatter_pass<<<PB, PT, 0, stream>>>(src, dst, blockHist, pedge);
    deg_dis<<<NB, B, 0, stream>>>(pedge, bucketStart, dis);

    // conv1
    gemm_x_w1<<<cdiv(NN, 16), B, 0, stream>>>(x, W1, dis, bufA);
    agg16<<<NB, B, 0, stream>>>(pedge, bucketStart, dis, bufA, b1, 1, bufB);

    // conv3
    gemm_h_w16<<<cdiv(NN, 16), B, 0, stream>>>(bufB, W3, dis, bufA);
    agg16<<<NB, B, 0, stream>>>(pedge, bucketStart, dis, bufA, b3, 1, bufB);

    // conv2 + log_softmax
    gemm_h_w2<<<cdiv((long long)NN * DOUT, B), B, 0, stream>>>(bufB, W2, dis, bufA);
    agg2_lsm<<<NB, B, 0, stream>>>(pedge, bucketStart, dis, bufA, b2, out);
}

// Round 4
// 1455.430 us; speedup vs baseline: 1.0303x; 1.0303x over previous
//
#include <hip/hip_runtime.h>

#define NN 200000
#define NE 5000000
#define DIN 128
#define HID 16
#define DOUT 2
#define NB 782   // ceil(NN/256) buckets of 256 consecutive dst nodes
#define PB 512   // partition grid blocks
#define PT 256   // partition block threads

static_assert((NN + 255) / 256 == NB, "bucket count");

// ---------------- edge partition (counting sort by dst>>8, no global atomics) ----------------

__global__ __launch_bounds__(PT) void hist_pass(const int* __restrict__ dst,
                                                int* __restrict__ blockHist) {
    __shared__ int h[NB];
    for (int k = threadIdx.x; k < NB; k += PT) h[k] = 0;
    __syncthreads();
    for (int i = blockIdx.x * PT + threadIdx.x; i < NE; i += PB * PT)
        atomicAdd(&h[dst[i] >> 8], 1);
    __syncthreads();
    for (int k = threadIdx.x; k < NB; k += PT) blockHist[k * PB + blockIdx.x] = h[k];
}

__global__ __launch_bounds__(1024) void scan_pass(int* __restrict__ blockHist,
                                                  int* __restrict__ bucketStart) {
    __shared__ int tot[NB];
    for (int k = threadIdx.x; k < NB; k += 1024) {
        const int4* p = reinterpret_cast<const int4*>(blockHist + k * PB);
        int s = 0;
#pragma unroll 8
        for (int b = 0; b < PB / 4; ++b) { int4 v = p[b]; s += v.x + v.y + v.z + v.w; }
        tot[k] = s;
    }
    __syncthreads();
    if (threadIdx.x == 0) {
        int car = 0;
        for (int k = 0; k < NB; ++k) { int t = tot[k]; tot[k] = car; car += t; }
    }
    __syncthreads();
    for (int k = threadIdx.x; k < NB; k += 1024) {
        int run = tot[k];
        bucketStart[k] = run;
        int4* p = reinterpret_cast<int4*>(blockHist + k * PB);
#pragma unroll 4
        for (int b = 0; b < PB / 4; ++b) {
            int4 v = p[b];
            int4 o;
            o.x = run; run += v.x;
            o.y = run; run += v.y;
            o.z = run; run += v.z;
            o.w = run; run += v.w;
            p[b] = o;
        }
    }
    if (threadIdx.x == 0) bucketStart[NB] = NE;
}

__global__ __launch_bounds__(PT) void scatter_pass(const int* __restrict__ src,
                                                   const int* __restrict__ dst,
                                                   const int* __restrict__ blockHist,
                                                   unsigned* __restrict__ pedge) {
    __shared__ int cur[NB];
    for (int k = threadIdx.x; k < NB; k += PT) cur[k] = blockHist[k * PB + blockIdx.x];
    __syncthreads();
    for (int i = blockIdx.x * PT + threadIdx.x; i < NE; i += PB * PT) {
        int d = dst[i];
        int pos = atomicAdd(&cur[d >> 8], 1);  // LDS atomic only
        pedge[pos] = ((unsigned)src[i] << 8) | (unsigned)(d & 255);
    }
}

__global__ __launch_bounds__(256) void deg_dis(const unsigned* __restrict__ pedge,
                                               const int* __restrict__ bucketStart,
                                               float* __restrict__ dis) {
    __shared__ int cnt[256];
    int t = threadIdx.x;
    cnt[t] = 1;  // self loop
    __syncthreads();
    int e0 = bucketStart[blockIdx.x], e1 = bucketStart[blockIdx.x + 1];
    for (int e = e0 + t; e < e1; e += 256) atomicAdd(&cnt[pedge[e] & 255u], 1);
    __syncthreads();
    int node = (blockIdx.x << 8) + t;
    if (node < NN) dis[node] = rsqrtf((float)cnt[t]);
}

// ---------------- dense GEMMs, epilogue-scaled by dis[row] ----------------

__global__ __launch_bounds__(256) void gemm_x_w1(const float* __restrict__ x,
                                                 const float* __restrict__ W,
                                                 const float* __restrict__ dis,
                                                 float* __restrict__ out) {
    __shared__ float w[DIN * HID];
    for (int t = threadIdx.x; t < DIN * HID; t += 256) w[t] = W[t];
    __syncthreads();
    int row = blockIdx.x * 16 + (threadIdx.x >> 4);
    int c = threadIdx.x & 15;
    if (row >= NN) return;
    const float4* xr = reinterpret_cast<const float4*>(x + (size_t)row * DIN);
    float acc = 0.f;
#pragma unroll
    for (int k4 = 0; k4 < DIN / 4; ++k4) {
        float4 v = xr[k4];
        acc += v.x * w[(4 * k4 + 0) * HID + c] + v.y * w[(4 * k4 + 1) * HID + c]
             + v.z * w[(4 * k4 + 2) * HID + c] + v.w * w[(4 * k4 + 3) * HID + c];
    }
    out[row * HID + c] = acc * dis[row];
}

__global__ __launch_bounds__(256) void gemm_h_w16(const float* __restrict__ h,
                                                  const float* __restrict__ W,
                                                  const float* __restrict__ dis,
                                                  float* __restrict__ out) {
    __shared__ float w[HID * HID];
    if (threadIdx.x < HID * HID) w[threadIdx.x] = W[threadIdx.x];
    __syncthreads();
    int row = blockIdx.x * 16 + (threadIdx.x >> 4);
    int c = threadIdx.x & 15;
    if (row >= NN) return;
    const float4* hr = reinterpret_cast<const float4*>(h + (size_t)row * HID);
    float acc = 0.f;
#pragma unroll
    for (int k4 = 0; k4 < HID / 4; ++k4) {
        float4 v = hr[k4];
        acc += v.x * w[(4 * k4 + 0) * HID + c] + v.y * w[(4 * k4 + 1) * HID + c]
             + v.z * w[(4 * k4 + 2) * HID + c] + v.w * w[(4 * k4 + 3) * HID + c];
    }
    out[row * HID + c] = acc * dis[row];
}

__global__ __launch_bounds__(256) void gemm_h_w2(const float* __restrict__ h,
                                                 const float* __restrict__ W,
                                                 const float* __restrict__ dis,
                                                 float* __restrict__ out) {
    int t = blockIdx.x * 256 + threadIdx.x;
    int row = t >> 1;
    int c = t & 1;
    if (row >= NN) return;
    const float* hr = h + (size_t)row * HID;
    float acc = 0.f;
#pragma unroll
    for (int k = 0; k < HID; ++k) acc += hr[k] * W[k * DOUT + c];
    out[row * DOUT + c] = acc * dis[row];
}

// ---------------- bucket-local aggregation (LDS atomics only) ----------------

// 1024 threads = 64 edge-streams of 16 lanes; 4x unrolled gathers for MLP.
__global__ __launch_bounds__(1024) void agg16(const unsigned* __restrict__ pedge,
                                              const int* __restrict__ bucketStart,
                                              const float* __restrict__ dis,
                                              const float* __restrict__ xs,
                                              const float* __restrict__ bias, int relu,
                                              float* __restrict__ out) {
    __shared__ float acc[256 * HID];  // 16 KB
    __shared__ float dl[256];
    int t = threadIdx.x;
    int base = blockIdx.x << 8;
    if (t < 256) {
        int node = base + t;
        dl[t] = (node < NN) ? dis[node] : 0.f;
    }
    __syncthreads();
    for (int i = t; i < 256 * HID; i += 1024) {  // self-loop init: xs[node]*dis[node]
        int gi = (base << 4) + i;
        acc[i] = (gi < NN * HID) ? xs[gi] * dl[i >> 4] : 0.f;
    }
    __syncthreads();
    int e0 = bucketStart[blockIdx.x], e1 = bucketStart[blockIdx.x + 1];
    int c = t & 15;
    const int NS = 64;           // edge streams per block
    int e = e0 + (t >> 4);
    for (; e + 3 * NS < e1; e += 4 * NS) {  // 4 gathers in flight per stream
        unsigned p0 = pedge[e];
        unsigned p1 = pedge[e + NS];
        unsigned p2 = pedge[e + 2 * NS];
        unsigned p3 = pedge[e + 3 * NS];
        float v0 = xs[((p0 >> 8) << 4) + c];
        float v1 = xs[((p1 >> 8) << 4) + c];
        float v2 = xs[((p2 >> 8) << 4) + c];
        float v3 = xs[((p3 >> 8) << 4) + c];
        int d0 = p0 & 255u, d1 = p1 & 255u, d2 = p2 & 255u, d3 = p3 & 255u;
        atomicAdd(&acc[(d0 << 4) + c], v0 * dl[d0]);
        atomicAdd(&acc[(d1 << 4) + c], v1 * dl[d1]);
        atomicAdd(&acc[(d2 << 4) + c], v2 * dl[d2]);
        atomicAdd(&acc[(d3 << 4) + c], v3 * dl[d3]);
    }
    for (; e < e1; e += NS) {
        unsigned p = pedge[e];
        int d = p & 255u;
        atomicAdd(&acc[(d << 4) + c], xs[((p >> 8) << 4) + c] * dl[d]);
    }
    __syncthreads();
    for (int i = t; i < 256 * HID; i += 1024) {
        int gi = (base << 4) + i;
        if (gi < NN * HID) {
            float v = acc[i] + bias[i & 15];
            out[gi] = relu ? fmaxf(v, 0.f) : v;
        }
    }
}

// conv2 aggregation + bias + 2-class log_softmax. 1024 threads = 512 streams.
__global__ __launch_bounds__(1024) void agg2_lsm(const unsigned* __restrict__ pedge,
                                                 const int* __restrict__ bucketStart,
                                                 const float* __restrict__ dis,
                                                 const float* __restrict__ xs,
                                                 const float* __restrict__ bias,
                                                 float* __restrict__ out) {
    __shared__ float acc[256 * DOUT];
    __shared__ float dl[256];
    int t = threadIdx.x;
    int base = blockIdx.x << 8;
    if (t < 256) {
        int node = base + t;
        float d0 = (node < NN) ? dis[node] : 0.f;
        dl[t] = d0;
        if (node < NN) {
            float2 v = reinterpret_cast<const float2*>(xs)[node];
            acc[t * 2 + 0] = v.x * d0;
            acc[t * 2 + 1] = v.y * d0;
        } else {
            acc[t * 2 + 0] = 0.f;
            acc[t * 2 + 1] = 0.f;
        }
    }
    __syncthreads();
    int e0 = bucketStart[blockIdx.x], e1 = bucketStart[blockIdx.x + 1];
    int c = t & 1;
    const int NS = 512;
    int e = e0 + (t >> 1);
    for (; e + 3 * NS < e1; e += 4 * NS) {
        unsigned p0 = pedge[e];
        unsigned p1 = pedge[e + NS];
        unsigned p2 = pedge[e + 2 * NS];
        unsigned p3 = pedge[e + 3 * NS];
        float v0 = xs[(p0 >> 8) * 2 + c];
        float v1 = xs[(p1 >> 8) * 2 + c];
        float v2 = xs[(p2 >> 8) * 2 + c];
        float v3 = xs[(p3 >> 8) * 2 + c];
        int d0 = p0 & 255u, d1 = p1 & 255u, d2 = p2 & 255u, d3 = p3 & 255u;
        atomicAdd(&acc[d0 * 2 + c], v0 * dl[d0]);
        atomicAdd(&acc[d1 * 2 + c], v1 * dl[d1]);
        atomicAdd(&acc[d2 * 2 + c], v2 * dl[d2]);
        atomicAdd(&acc[d3 * 2 + c], v3 * dl[d3]);
    }
    for (; e < e1; e += NS) {
        unsigned p = pedge[e];
        int d = p & 255u;
        atomicAdd(&acc[d * 2 + c], xs[(p >> 8) * 2 + c] * dl[d]);
    }
    __syncthreads();
    if (t < 256) {
        int node = base + t;
        if (node < NN) {
            float v0 = acc[t * 2 + 0] + bias[0];
            float v1 = acc[t * 2 + 1] + bias[1];
            float m = fmaxf(v0, v1);
            float lse = m + logf(__expf(v0 - m) + __expf(v1 - m));
            reinterpret_cast<float2*>(out)[node] = make_float2(v0 - lse, v1 - lse);
        }
    }
}

// ---------------- launch ----------------

extern "C" void kernel_launch(void* const* d_in, const int* in_sizes, int n_in,
                              void* d_out, int out_size, void* d_ws, size_t ws_size,
                              hipStream_t stream) {
    const float* x = (const float*)d_in[0];
    const int* ei = (const int*)d_in[1];
    const float* W1 = (const float*)d_in[2];
    const float* b1 = (const float*)d_in[3];
    const float* W3 = (const float*)d_in[4];
    const float* b3 = (const float*)d_in[5];
    const float* W2 = (const float*)d_in[6];
    const float* b2 = (const float*)d_in[7];
    float* out = (float*)d_out;

    const int* src = ei;       // edge_index[0]
    const int* dst = ei + NE;  // edge_index[1]

    // workspace layout
    char* ws = (char*)d_ws;
    unsigned* pedge = (unsigned*)ws;                      // NE
    int* blockHist = (int*)(ws + sizeof(unsigned) * NE);  // NB*PB
    int* bucketStart = blockHist + NB * PB;               // NB+1
    float* dis = (float*)(bucketStart + NB + 1);          // NN
    float* bufA = dis + NN;                               // NN*HID
    float* bufB = bufA + NN * HID;                        // NN*HID

    const int B = 256;
    auto cdiv = [](long long a, long long b) { return (int)((a + b - 1) / b); };

    // partition + normalization
    hist_pass<<<PB, PT, 0, stream>>>(dst, blockHist);
    scan_pass<<<1, 1024, 0, stream>>>(blockHist, bucketStart);
    scatter_pass<<<PB, PT, 0, stream>>>(src, dst, blockHist, pedge);
    deg_dis<<<NB, B, 0, stream>>>(pedge, bucketStart, dis);

    // conv1
    gemm_x_w1<<<cdiv(NN, 16), B, 0, stream>>>(x, W1, dis, bufA);
    agg16<<<NB, 1024, 0, stream>>>(pedge, bucketStart, dis, bufA, b1, 1, bufB);

    // conv3
    gemm_h_w16<<<cdiv(NN, 16), B, 0, stream>>>(bufB, W3, dis, bufA);
    agg16<<<NB, 1024, 0, stream>>>(pedge, bucketStart, dis, bufA, b3, 1, bufB);

    // conv2 + log_softmax
    gemm_h_w2<<<cdiv((long long)NN * DOUT, B), B, 0, stream>>>(bufB, W2, dis, bufA);
    agg2_lsm<<<NB, 1024, 0, stream>>>(pedge, bucketStart, dis, bufA, b2, out);
}